// Round 19
// baseline (224.582 us; speedup 1.0000x reference)
//
#include <hip/hip_runtime.h>
#include <hip/hip_bf16.h>

// Problem constants: B=4,T=8,L=512,C=768,H=8,HD=96.  M = B*T*L = 16384.

typedef __attribute__((ext_vector_type(8))) short bf16x8;
typedef __attribute__((ext_vector_type(4))) float f32x4;
typedef __attribute__((ext_vector_type(4))) int int4v;

__device__ __forceinline__ float b2f(unsigned short u) {
    return __uint_as_float(((unsigned)u) << 16);
}
__device__ __forceinline__ unsigned short f2b(float f) {
    unsigned u = __float_as_uint(f);
    u = (u + 0x7fffu + ((u >> 16) & 1u)) >> 16;   // RNE
    return (unsigned short)u;
}

__device__ __forceinline__ void gll16(const unsigned short* g, unsigned short* l) {
    __builtin_amdgcn_global_load_lds((const __attribute__((address_space(1))) unsigned int*)g,
                                     (__attribute__((address_space(3))) unsigned int*)l, 16, 0, 0);
}

#define VMCNT(n) asm volatile("s_waitcnt vmcnt(" #n ")" ::: "memory")
#define BAR()    __builtin_amdgcn_s_barrier()
#define SCHED0() __builtin_amdgcn_sched_barrier(0)
#define PRIO(x)  __builtin_amdgcn_s_setprio(x)

// ---------------- fused prep: cast x->bf16 (blocks 0..12287) + pack W^T (blocks 12288..12863) ----------------
__global__ __launch_bounds__(256) void prep_k(const float* __restrict__ x,
                                              unsigned short* __restrict__ xb,
                                              const float* __restrict__ Wq,
                                              const float* __restrict__ Wkv,
                                              const float* __restrict__ Wm,
                                              unsigned short* __restrict__ Wt) {
    __shared__ float tile[64][65];
    const int tid = threadIdx.x;
    if (blockIdx.x < 12288) {
        const int i = blockIdx.x * 256 + tid;
        float4 v = ((const float4*)x)[i];
        ushort4 o;
        o.x = f2b(v.x); o.y = f2b(v.y); o.z = f2b(v.z); o.w = f2b(v.w);
        ((ushort4*)xb)[i] = o;
        return;
    }
    const int pb = blockIdx.x - 12288;
    const int tn = pb % 48;
    const int tk = pb / 48;
    const int n0 = tn * 64, k0 = tk * 64;
    const float* src; int ldn, coff;
    if (n0 < 768)       { src = Wq;  ldn = 768;  coff = n0; }
    else if (n0 < 2304) { src = Wkv; ldn = 1536; coff = n0 - 768; }
    else                { src = Wm;  ldn = 768;  coff = n0 - 2304; }
    const int j = tid & 63;
    for (int i = tid >> 6; i < 64; i += 4)
        tile[i][j] = src[(k0 + i) * ldn + coff + j];
    __syncthreads();
    const int ii = tid & 63;
    for (int jj = tid >> 6; jj < 64; jj += 4)
        Wt[(long)(n0 + jj) * 768 + k0 + ii] = f2b(tile[ii][jj]);
}

// ---------------- 256x128 pipelined GEMM, 3-buffer LDS, 2 blocks/CU (r5 known-good, 77us) ----------------
template <int EPI>
__global__ __launch_bounds__(512, 4) void gemm_k(const unsigned short* __restrict__ A,
                                                 const unsigned short* __restrict__ Bt,
                                                 const float* __restrict__ bias0,
                                                 const float* __restrict__ bias1,
                                                 unsigned short* __restrict__ Cb,
                                                 float* __restrict__ Cf,
                                                 int N, int K, int nbn) {
    extern __shared__ unsigned short lds[];   // 3 x 12288 ushorts
    const int tid = threadIdx.x;
    const int lane = tid & 63, wid = tid >> 6;
    const int wm = wid >> 1, wn = wid & 1;
    const int l15 = lane & 15, g = lane >> 4;

    const int nwg = gridDim.x;
    const int wg = (blockIdx.x & 7) * (nwg >> 3) + (blockIdx.x >> 3);
    const int bm = wg / nbn, bn = wg % nbn;

    const unsigned short* gA = A  + (long)bm * 256 * K;
    const unsigned short* gB = Bt + (long)bn * 128 * K;

    const long sgoff = (long)(tid >> 2) * K + (long)(((tid & 3) ^ ((tid >> 3) & 3)) * 8);
    const int swoff = wid * 512;

#define STAGE_ALL(T, BUFO) do { \
        const long kb0 = (long)(T) * 32; \
        gll16(gB + sgoff + kb0, lds + (BUFO) + 8192 + swoff); \
        gll16(gA + sgoff + kb0, lds + (BUFO) + swoff); \
        gll16(gA + sgoff + kb0 + (long)128 * K, lds + (BUFO) + 4096 + swoff); \
    } while (0)

    const int slot8 = (g ^ ((l15 >> 1) & 3)) * 8;
    f32x4 acc[4][4] = {};
    const int nkt = K >> 5;

    STAGE_ALL(0, 0);
    STAGE_ALL(1, 12288);

    int cur = 0, nx1 = 12288, nx2 = 24576;
    for (int t = 0; t < nkt; ++t) {
        if (t < nkt - 1) { VMCNT(3); } else { VMCNT(0); }
        BAR(); SCHED0();
        if (t + 2 < nkt) STAGE_ALL(t + 2, nx2);

        bf16x8 af[4], bv[4];
#pragma unroll
        for (int mf = 0; mf < 4; mf++)
            af[mf] = *(const bf16x8*)&lds[cur + (wm * 64 + mf * 16 + l15) * 32 + slot8];
#pragma unroll
        for (int nf = 0; nf < 4; nf++)
            bv[nf] = *(const bf16x8*)&lds[cur + 8192 + (wn * 64 + nf * 16 + l15) * 32 + slot8];
        PRIO(1);
#pragma unroll
        for (int mf = 0; mf < 4; mf++)
#pragma unroll
            for (int nf = 0; nf < 4; nf++)
                acc[mf][nf] = __builtin_amdgcn_mfma_f32_16x16x32_bf16(af[mf], bv[nf], acc[mf][nf], 0, 0, 0);
        PRIO(0);
        const int tmp = cur; cur = nx1; nx1 = nx2; nx2 = tmp;
    }
#undef STAGE_ALL

    float bvv[4];
#pragma unroll
    for (int nf = 0; nf < 4; nf++) {
        const int col = bn * 128 + wn * 64 + nf * 16 + l15;
        bvv[nf] = (EPI == 0) ? ((col < 768) ? bias0[col] : bias1[col - 768]) : bias0[col];
    }
#pragma unroll
    for (int mf = 0; mf < 4; mf++) {
#pragma unroll
        for (int r = 0; r < 4; r++) {
            const long row = bm * 256 + wm * 64 + mf * 16 + g * 4 + r;
#pragma unroll
            for (int nf = 0; nf < 4; nf++) {
                const float v = acc[mf][nf][r] + bvv[nf];
                if (EPI == 0) {
                    const unsigned hh = f2b(v);
                    const unsigned oo = __shfl_xor((int)hh, 1);
                    if (!(lane & 1))
                        *(unsigned*)&Cb[row * N + bn * 128 + wn * 64 + nf * 16 + l15] =
                            (hh & 0xffffu) | (oo << 16);
                } else {
                    Cf[row * N + bn * 128 + wn * 64 + nf * 16 + l15] = v;
                }
            }
        }
    }
}

// ---------------- 128x128 GEMM for the output projection (fp32 out), 3 blocks/CU ----------------
__global__ __launch_bounds__(512, 6) void gemm128_k(const unsigned short* __restrict__ A,
                                                    const unsigned short* __restrict__ Bt,
                                                    const float* __restrict__ bias0,
                                                    float* __restrict__ Cf,
                                                    int N, int K, int nbn) {
    extern __shared__ unsigned short lds[];   // 3 x 8192 ushorts (A 4096 + B 4096)
    const int tid = threadIdx.x;
    const int lane = tid & 63, wid = tid >> 6;
    const int wm = wid >> 2, wn = wid & 3;
    const int l15 = lane & 15, g = lane >> 4;

    const int nwg = gridDim.x;
    const int wg = (blockIdx.x & 7) * (nwg >> 3) + (blockIdx.x >> 3);
    const int bm = wg / nbn, bn = wg % nbn;

    const unsigned short* gA = A  + (long)bm * 128 * K;
    const unsigned short* gB = Bt + (long)bn * 128 * K;

    const long sgoff = (long)(tid >> 2) * K + (long)(((tid & 3) ^ ((tid >> 3) & 3)) * 8);
    const int swoff = wid * 512;

#define STAGE2(T, BUFO) do { \
        const long kb0 = (long)(T) * 32; \
        gll16(gB + sgoff + kb0, lds + (BUFO) + 4096 + swoff); \
        gll16(gA + sgoff + kb0, lds + (BUFO) + swoff); \
    } while (0)

    const int slot8 = (g ^ ((l15 >> 1) & 3)) * 8;
    f32x4 acc[4][2] = {};
    const int nkt = K >> 5;

    STAGE2(0, 0);
    STAGE2(1, 8192);

    int cur = 0, nx1 = 8192, nx2 = 16384;
    for (int t = 0; t < nkt; ++t) {
        if (t < nkt - 1) { VMCNT(2); } else { VMCNT(0); }
        BAR(); SCHED0();
        if (t + 2 < nkt) STAGE2(t + 2, nx2);

        bf16x8 af[4], bv[2];
#pragma unroll
        for (int mf = 0; mf < 4; mf++)
            af[mf] = *(const bf16x8*)&lds[cur + (wm * 64 + mf * 16 + l15) * 32 + slot8];
#pragma unroll
        for (int nf = 0; nf < 2; nf++)
            bv[nf] = *(const bf16x8*)&lds[cur + 4096 + (wn * 32 + nf * 16 + l15) * 32 + slot8];
        PRIO(1);
#pragma unroll
        for (int mf = 0; mf < 4; mf++)
#pragma unroll
            for (int nf = 0; nf < 2; nf++)
                acc[mf][nf] = __builtin_amdgcn_mfma_f32_16x16x32_bf16(af[mf], bv[nf], acc[mf][nf], 0, 0, 0);
        PRIO(0);
        const int tmp = cur; cur = nx1; nx1 = nx2; nx2 = tmp;
    }
#undef STAGE2

    float bvv[2];
#pragma unroll
    for (int nf = 0; nf < 2; nf++)
        bvv[nf] = bias0[bn * 128 + wn * 32 + nf * 16 + l15];
#pragma unroll
    for (int mf = 0; mf < 4; mf++) {
#pragma unroll
        for (int r = 0; r < 4; r++) {
            const long row = bm * 128 + wm * 64 + mf * 16 + g * 4 + r;
#pragma unroll
            for (int nf = 0; nf < 2; nf++)
                Cf[row * N + bn * 128 + wn * 32 + nf * 16 + l15] = acc[mf][nf][r] + bvv[nf];
        }
    }
}

// ---------------- k/v inverse-norm tables (2 segments per wave) ----------------
__global__ __launch_bounds__(256) void knvn_k(const unsigned short* __restrict__ qkv,
                                              float* __restrict__ kinv,
                                              float* __restrict__ vinv) {
    const int tid = threadIdx.x, lane = tid & 63, w = tid >> 6;
#pragma unroll
    for (int q = 0; q < 2; q++) {
        const int s = blockIdx.x * 8 + w * 2 + q;
        const int row = s >> 3, h = s & 7;
        const unsigned short* pk = qkv + (long)row * 2304 + 768 + h * 96;
        float k0 = 0.f, k1 = 0.f, v0 = 0.f, v1 = 0.f;
        if (lane < 48) {
            unsigned a = *(const unsigned*)(pk + lane * 2);
            unsigned b = *(const unsigned*)(pk + 768 + lane * 2);
            k0 = b2f((unsigned short)(a & 0xffffu)); k1 = b2f((unsigned short)(a >> 16));
            v0 = b2f((unsigned short)(b & 0xffffu)); v1 = b2f((unsigned short)(b >> 16));
        }
        float sk = k0 * k0 + k1 * k1;
        float sv = v0 * v0 + v1 * v1;
#pragma unroll
        for (int m = 1; m < 64; m <<= 1) { sk += __shfl_xor(sk, m); sv += __shfl_xor(sv, m); }
        if (lane == 0) {
            kinv[h * 16384 + row] = 1.f / fmaxf(sqrtf(sk), 1e-12f);
            vinv[h * 16384 + row] = 1.f / fmaxf(sqrtf(sv), 1e-12f);
        }
    }
}

// ---------------- fused attention per (bt, head, 128-row q-block) ----------------
// r18 structure (double-buffered K/V, 1 barrier/tile, Q global->reg, slim Ps,
// T14 split-wave prefetch, T5 setprio) + exp2 fold + deferred l-reduction.
__global__ __launch_bounds__(512, 2) void attn_k(const unsigned short* __restrict__ qkv,
                                                 const float* __restrict__ kinv,
                                                 const float* __restrict__ vinv,
                                                 unsigned short* __restrict__ obuf) {
    constexpr float SCALE = 0.1020620726159658f;   // 1/sqrt(96)
    constexpr float LOG2E = 1.4426950408889634f;
    __shared__ unsigned short Ps[128 * 72];        // P' (rows owned per wave)
    __shared__ unsigned short Ks[2][64 * 104];     // K tiles, double-buffered
    __shared__ unsigned short Vt[2][96 * 72];      // V^T tiles, double-buffered
    __shared__ float kinv_s[2][64], vinv_s[2][64];

    const int tid = threadIdx.x, lane = tid & 63, w = tid >> 6;
    const int bid0 = blockIdx.x;
    const int bid = (bid0 & 7) * 128 + (bid0 >> 3);   // XCD swizzle (1024 % 8 == 0)
    const int qt = bid & 3, h = (bid >> 2) & 7, bt = bid >> 5;
    const long rowbase = (long)bt * 512 * 2304 + h * 96;
    const int l15 = lane & 15;
    const int g = lane >> 4;
    const int ko = g * 8;

    // ---- Q fragments: straight from global (row = qt*128 + w*16 + l15, L2-warm) ----
    bf16x8 qf[3];
    {
        const unsigned short* qrow = qkv + rowbase + (long)(qt * 128 + w * 16 + l15) * 2304;
#pragma unroll
        for (int ks = 0; ks < 3; ks++)
            qf[ks] = *(const bf16x8*)&qrow[ks * 32 + ko];
    }

    // ---- stage K/V tile 0 into buffer 0 (split-wave, paired-key V transpose) ----
    if (tid < 256) {
#pragma unroll
        for (int j = 0; j < 3; j++) {
            const int c = tid + j * 256;
            const int r = c / 12, d8 = (c % 12) * 8;
            *(int4v*)&Ks[0][r * 104 + d8] = *(const int4v*)&qkv[rowbase + 768 + (long)r * 2304 + d8];
        }
    } else {
        const int tid2 = tid - 256;
#pragma unroll
        for (int j = 0; j < 2; j++) {
            const int c = tid2 + j * 256;
            if (c < 384) {
                const int kp = c & 31, d8c = c >> 5;
                const unsigned short* vsrc = &qkv[rowbase + 1536 + (long)(2 * kp) * 2304 + d8c * 8];
                int4v v0 = *(const int4v*)vsrc;
                int4v v1 = *(const int4v*)(vsrc + 2304);
                const unsigned short* p0 = (const unsigned short*)&v0;
                const unsigned short* p1 = (const unsigned short*)&v1;
#pragma unroll
                for (int i = 0; i < 8; i++)
                    *(unsigned*)&Vt[0][(d8c * 8 + i) * 72 + 2 * kp] =
                        (unsigned)p0[i] | ((unsigned)p1[i] << 16);
            }
        }
    }
    if (tid < 64)       kinv_s[0][tid]      = kinv[h * 16384 + bt * 512 + tid];
    else if (tid < 128) vinv_s[0][tid - 64] = vinv[h * 16384 + bt * 512 + tid - 64];
    __syncthreads();

    // q-row scale = SCALE·log2e / ||q_row|| (f32); exp2 replaces exp
    float ssq = 0.f;
#pragma unroll
    for (int ks = 0; ks < 3; ks++)
#pragma unroll
        for (int j = 0; j < 8; j++) {
            const float f = b2f((unsigned short)qf[ks][j]);
            ssq += f * f;
        }
    ssq += __shfl_xor(ssq, 16);
    ssq += __shfl_xor(ssq, 32);
    const float qs2 = (SCALE * LOG2E) / fmaxf(sqrtf(ssq), 1e-12f);

    float l_part = 0.f;   // per-lane partial; cross-lane reduce deferred to after the loop
    f32x4 oacc[6] = {};

    for (int kt = 0; kt < 8; kt++) {
        const int cb = kt & 1, nb = cb ^ 1;

        // ---- T14: prefetch next K/V tile into registers ----
        int4v preg[4];
        float tn = 0.f;
        if (kt < 7) {
            if (tid < 256) {
                const long kb = rowbase + 768 + (long)((kt + 1) * 64) * 2304;
#pragma unroll
                for (int j = 0; j < 3; j++) {
                    const int c = tid + j * 256;
                    preg[j] = *(const int4v*)&qkv[kb + (long)(c / 12) * 2304 + (c % 12) * 8];
                }
            } else {
                const int tid2 = tid - 256;
                const long vb = rowbase + 1536 + (long)((kt + 1) * 64) * 2304;
#pragma unroll
                for (int j = 0; j < 2; j++) {
                    const int c = tid2 + j * 256;
                    if (c < 384) {
                        const int kp = c & 31, d8c = c >> 5;
                        const unsigned short* vsrc = &qkv[vb + (long)(2 * kp) * 2304 + d8c * 8];
                        preg[2 * j]     = *(const int4v*)vsrc;
                        preg[2 * j + 1] = *(const int4v*)(vsrc + 2304);
                    }
                }
            }
            if (tid < 64)       tn = kinv[h * 16384 + bt * 512 + (kt + 1) * 64 + tid];
            else if (tid < 128) tn = vinv[h * 16384 + bt * 512 + (kt + 1) * 64 + tid - 64];
        }

        // ---- S^T = mfma(K_raw, Q_raw): rows = key, cols = q ----
        f32x4 sacc[4] = {};
        PRIO(1);
#pragma unroll
        for (int ks = 0; ks < 3; ks++) {
#pragma unroll
            for (int kf = 0; kf < 4; kf++) {
                bf16x8 af = *(const bf16x8*)&Ks[cb][(kf * 16 + l15) * 104 + ks * 32 + ko];
                sacc[kf] = __builtin_amdgcn_mfma_f32_16x16x32_bf16(af, qf[ks], sacc[kf], 0, 0, 0);
            }
        }
        PRIO(0);

        // ---- softmax without max: p = exp2(s*qs2*kinv); fold vinv into P' ----
        float p[16];
#pragma unroll
        for (int kf = 0; kf < 4; kf++)
#pragma unroll
            for (int r = 0; r < 4; r++) {
                const float pv = exp2f(sacc[kf][r] * qs2 * kinv_s[cb][kf * 16 + g * 4 + r]);
                l_part += pv;
                p[kf * 4 + r] = pv * vinv_s[cb][kf * 16 + g * 4 + r];
            }

        // ---- pack P' (row q = w*16+l15, cols keys) into Ps, paired u32 (wave-local) ----
        {
            unsigned* prow = (unsigned*)&Ps[(w * 16 + l15) * 72];
#pragma unroll
            for (int kf = 0; kf < 4; kf++)
#pragma unroll
                for (int rp = 0; rp < 2; rp++) {
                    unsigned pk = (unsigned)f2b(p[kf * 4 + 2 * rp]) |
                                  ((unsigned)f2b(p[kf * 4 + 2 * rp + 1]) << 16);
                    prow[kf * 8 + g * 2 + rp] = pk;
                }
        }

        // ---- O += P' * V_raw ----
        PRIO(1);
#pragma unroll
        for (int ks = 0; ks < 2; ks++) {
            bf16x8 pa = *(const bf16x8*)&Ps[(w * 16 + l15) * 72 + ks * 32 + ko];
#pragma unroll
            for (int nf = 0; nf < 6; nf++) {
                bf16x8 vb = *(const bf16x8*)&Vt[cb][(nf * 16 + l15) * 72 + ks * 32 + ko];
                oacc[nf] = __builtin_amdgcn_mfma_f32_16x16x32_bf16(pa, vb, oacc[nf], 0, 0, 0);
            }
        }
        PRIO(0);

        // ---- write prefetched regs -> buffer nb (disjoint from cb readers), then ONE barrier ----
        if (kt < 7) {
            if (tid < 256) {
#pragma unroll
                for (int j = 0; j < 3; j++) {
                    const int c = tid + j * 256;
                    *(int4v*)&Ks[nb][(c / 12) * 104 + (c % 12) * 8] = preg[j];
                }
            } else {
                const int tid2 = tid - 256;
#pragma unroll
                for (int j = 0; j < 2; j++) {
                    const int c = tid2 + j * 256;
                    if (c < 384) {
                        const int kp = c & 31, d8c = c >> 5;
                        const unsigned short* p0 = (const unsigned short*)&preg[2 * j];
                        const unsigned short* p1 = (const unsigned short*)&preg[2 * j + 1];
#pragma unroll
                        for (int i = 0; i < 8; i++)
                            *(unsigned*)&Vt[nb][(d8c * 8 + i) * 72 + 2 * kp] =
                                (unsigned)p0[i] | ((unsigned)p1[i] << 16);
                    }
                }
            }
            if (tid < 64)       kinv_s[nb][tid]      = tn;
            else if (tid < 128) vinv_s[nb][tid - 64] = tn;
            __syncthreads();
        }
    }

    // ---- deferred cross-lane l reduction (sum reorder, f32-exact enough) ----
    float l_run = l_part;
    l_run += __shfl_xor(l_run, 16);
    l_run += __shfl_xor(l_run, 32);

    // ---- write O tile ----
    const float inv = 1.f / l_run;
    float invr[4];
#pragma unroll
    for (int r = 0; r < 4; r++) invr[r] = __shfl(inv, g * 4 + r);
#pragma unroll
    for (int r = 0; r < 4; r++) {
        const int row = w * 16 + g * 4 + r;
        const long gr = ((long)(bt * 512 + qt * 128 + row)) * 768 + h * 96;
#pragma unroll
        for (int nf = 0; nf < 6; nf++)
            obuf[gr + nf * 16 + l15] = f2b(oacc[nf][r] * invr[r]);
    }
}

extern "C" void kernel_launch(void* const* d_in, const int* in_sizes, int n_in,
                              void* d_out, int out_size, void* d_ws, size_t ws_size,
                              hipStream_t stream) {
    const float* x   = (const float*)d_in[0];
    const float* Wq  = (const float*)d_in[1];
    const float* bq  = (const float*)d_in[2];
    const float* Wkv = (const float*)d_in[3];
    const float* bkv = (const float*)d_in[4];
    const float* Wm  = (const float*)d_in[5];
    const float* bm  = (const float*)d_in[6];
    float* out = (float*)d_out;

    char* ws = (char*)d_ws;
    unsigned short* xb  = (unsigned short*)ws;                   // 16384x768 bf16 (dead after gemm0)
    float*          vinv = (float*)ws;                           // overlays xb: 512 KB
    float*          kinv = (float*)(ws + 524288);                // overlays xb: 512 KB
    unsigned short* wt  = (unsigned short*)(ws + 25165824);      // 3072x768 bf16
    unsigned short* qkv = (unsigned short*)(ws + 29884416);      // 16384x2304 bf16 (raw +bias)
    unsigned short* ob  = (unsigned short*)(ws + 105381888);     // 16384x768 bf16

    static bool attr_set = false;
    if (!attr_set) {
        hipFuncSetAttribute((const void*)gemm_k<0>, hipFuncAttributeMaxDynamicSharedMemorySize, 73728);
        hipFuncSetAttribute((const void*)gemm128_k, hipFuncAttributeMaxDynamicSharedMemorySize, 49152);
        attr_set = true;
    }

    // fused cast + weight pack (one launch)
    prep_k<<<dim3(12864), dim3(256), 0, stream>>>(x, xb, Wq, Wkv, Wm, wt);
    // QKV projection + bias: r5 3-buffer gemm (measured 77us), grid 64bm x 18bn = 1152
    gemm_k<0><<<dim3(1152), dim3(512), 73728, stream>>>(xb, wt, bq, bkv, qkv, nullptr, 2304, 768, 18);
    // k/v inverse-norm tables (2 segments/wave)
    knvn_k<<<dim3(16384), dim3(256), 0, stream>>>(qkv, kinv, vinv);
    // fused attention: double-buffered K/V, 1 barrier/tile, setprio, exp2, deferred l-reduce
    attn_k<<<dim3(1024), dim3(512), 0, stream>>>(qkv, kinv, vinv, ob);
    // output projection + bias -> fp32: grid 128bm x 6bn = 768
    gemm128_k<<<dim3(768), dim3(512), 49152, stream>>>(ob, wt + (long)2304 * 768, bm, out, 768, 768, 6);
}

// Round 20
// 192.875 us; speedup vs baseline: 1.1644x; 1.1644x over previous
//
#include <hip/hip_runtime.h>
#include <hip/hip_bf16.h>

// Problem constants: B=4,T=8,L=512,C=768,H=8,HD=96.  M = B*T*L = 16384.

typedef __attribute__((ext_vector_type(8))) short bf16x8;
typedef __attribute__((ext_vector_type(4))) float f32x4;
typedef __attribute__((ext_vector_type(4))) int int4v;

__device__ __forceinline__ float b2f(unsigned short u) {
    return __uint_as_float(((unsigned)u) << 16);
}
__device__ __forceinline__ unsigned short f2b(float f) {
    unsigned u = __float_as_uint(f);
    u = (u + 0x7fffu + ((u >> 16) & 1u)) >> 16;   // RNE
    return (unsigned short)u;
}

__device__ __forceinline__ void gll16(const unsigned short* g, unsigned short* l) {
    __builtin_amdgcn_global_load_lds((const __attribute__((address_space(1))) unsigned int*)g,
                                     (__attribute__((address_space(3))) unsigned int*)l, 16, 0, 0);
}

#define VMCNT(n) asm volatile("s_waitcnt vmcnt(" #n ")" ::: "memory")
#define BAR()    __builtin_amdgcn_s_barrier()
#define SCHED0() __builtin_amdgcn_sched_barrier(0)
#define PRIO(x)  __builtin_amdgcn_s_setprio(x)

// ---------------- fused prep: cast x->bf16 (blocks 0..12287) + pack W^T (blocks 12288..12863) ----------------
__global__ __launch_bounds__(256) void prep_k(const float* __restrict__ x,
                                              unsigned short* __restrict__ xb,
                                              const float* __restrict__ Wq,
                                              const float* __restrict__ Wkv,
                                              const float* __restrict__ Wm,
                                              unsigned short* __restrict__ Wt) {
    __shared__ float tile[64][65];
    const int tid = threadIdx.x;
    if (blockIdx.x < 12288) {
        const int i = blockIdx.x * 256 + tid;
        float4 v = ((const float4*)x)[i];
        ushort4 o;
        o.x = f2b(v.x); o.y = f2b(v.y); o.z = f2b(v.z); o.w = f2b(v.w);
        ((ushort4*)xb)[i] = o;
        return;
    }
    const int pb = blockIdx.x - 12288;
    const int tn = pb % 48;
    const int tk = pb / 48;
    const int n0 = tn * 64, k0 = tk * 64;
    const float* src; int ldn, coff;
    if (n0 < 768)       { src = Wq;  ldn = 768;  coff = n0; }
    else if (n0 < 2304) { src = Wkv; ldn = 1536; coff = n0 - 768; }
    else                { src = Wm;  ldn = 768;  coff = n0 - 2304; }
    const int j = tid & 63;
    for (int i = tid >> 6; i < 64; i += 4)
        tile[i][j] = src[(k0 + i) * ldn + coff + j];
    __syncthreads();
    const int ii = tid & 63;
    for (int jj = tid >> 6; jj < 64; jj += 4)
        Wt[(long)(n0 + jj) * 768 + k0 + ii] = f2b(tile[ii][jj]);
}

// ---------------- 256x128 pipelined GEMM, 3-buffer LDS, 2 blocks/CU (r5 known-good, 77us) ----------------
template <int EPI>
__global__ __launch_bounds__(512, 4) void gemm_k(const unsigned short* __restrict__ A,
                                                 const unsigned short* __restrict__ Bt,
                                                 const float* __restrict__ bias0,
                                                 const float* __restrict__ bias1,
                                                 unsigned short* __restrict__ Cb,
                                                 float* __restrict__ Cf,
                                                 int N, int K, int nbn) {
    extern __shared__ unsigned short lds[];   // 3 x 12288 ushorts
    const int tid = threadIdx.x;
    const int lane = tid & 63, wid = tid >> 6;
    const int wm = wid >> 1, wn = wid & 1;
    const int l15 = lane & 15, g = lane >> 4;

    const int nwg = gridDim.x;
    const int wg = (blockIdx.x & 7) * (nwg >> 3) + (blockIdx.x >> 3);
    const int bm = wg / nbn, bn = wg % nbn;

    const unsigned short* gA = A  + (long)bm * 256 * K;
    const unsigned short* gB = Bt + (long)bn * 128 * K;

    const long sgoff = (long)(tid >> 2) * K + (long)(((tid & 3) ^ ((tid >> 3) & 3)) * 8);
    const int swoff = wid * 512;

#define STAGE_ALL(T, BUFO) do { \
        const long kb0 = (long)(T) * 32; \
        gll16(gB + sgoff + kb0, lds + (BUFO) + 8192 + swoff); \
        gll16(gA + sgoff + kb0, lds + (BUFO) + swoff); \
        gll16(gA + sgoff + kb0 + (long)128 * K, lds + (BUFO) + 4096 + swoff); \
    } while (0)

    const int slot8 = (g ^ ((l15 >> 1) & 3)) * 8;
    f32x4 acc[4][4] = {};
    const int nkt = K >> 5;

    STAGE_ALL(0, 0);
    STAGE_ALL(1, 12288);

    int cur = 0, nx1 = 12288, nx2 = 24576;
    for (int t = 0; t < nkt; ++t) {
        if (t < nkt - 1) { VMCNT(3); } else { VMCNT(0); }
        BAR(); SCHED0();
        if (t + 2 < nkt) STAGE_ALL(t + 2, nx2);

        bf16x8 af[4], bv[4];
#pragma unroll
        for (int mf = 0; mf < 4; mf++)
            af[mf] = *(const bf16x8*)&lds[cur + (wm * 64 + mf * 16 + l15) * 32 + slot8];
#pragma unroll
        for (int nf = 0; nf < 4; nf++)
            bv[nf] = *(const bf16x8*)&lds[cur + 8192 + (wn * 64 + nf * 16 + l15) * 32 + slot8];
        PRIO(1);
#pragma unroll
        for (int mf = 0; mf < 4; mf++)
#pragma unroll
            for (int nf = 0; nf < 4; nf++)
                acc[mf][nf] = __builtin_amdgcn_mfma_f32_16x16x32_bf16(af[mf], bv[nf], acc[mf][nf], 0, 0, 0);
        PRIO(0);
        const int tmp = cur; cur = nx1; nx1 = nx2; nx2 = tmp;
    }
#undef STAGE_ALL

    float bvv[4];
#pragma unroll
    for (int nf = 0; nf < 4; nf++) {
        const int col = bn * 128 + wn * 64 + nf * 16 + l15;
        bvv[nf] = (EPI == 0) ? ((col < 768) ? bias0[col] : bias1[col - 768]) : bias0[col];
    }
#pragma unroll
    for (int mf = 0; mf < 4; mf++) {
#pragma unroll
        for (int r = 0; r < 4; r++) {
            const long row = bm * 256 + wm * 64 + mf * 16 + g * 4 + r;
#pragma unroll
            for (int nf = 0; nf < 4; nf++) {
                const float v = acc[mf][nf][r] + bvv[nf];
                if (EPI == 0) {
                    const unsigned hh = f2b(v);
                    const unsigned oo = __shfl_xor((int)hh, 1);
                    if (!(lane & 1))
                        *(unsigned*)&Cb[row * N + bn * 128 + wn * 64 + nf * 16 + l15] =
                            (hh & 0xffffu) | (oo << 16);
                } else {
                    Cf[row * N + bn * 128 + wn * 64 + nf * 16 + l15] = v;
                }
            }
        }
    }
}

// ---------------- 128x128 GEMM for the output projection (fp32 out), 3 blocks/CU ----------------
__global__ __launch_bounds__(512, 6) void gemm128_k(const unsigned short* __restrict__ A,
                                                    const unsigned short* __restrict__ Bt,
                                                    const float* __restrict__ bias0,
                                                    float* __restrict__ Cf,
                                                    int N, int K, int nbn) {
    extern __shared__ unsigned short lds[];   // 3 x 8192 ushorts (A 4096 + B 4096)
    const int tid = threadIdx.x;
    const int lane = tid & 63, wid = tid >> 6;
    const int wm = wid >> 2, wn = wid & 3;
    const int l15 = lane & 15, g = lane >> 4;

    const int nwg = gridDim.x;
    const int wg = (blockIdx.x & 7) * (nwg >> 3) + (blockIdx.x >> 3);
    const int bm = wg / nbn, bn = wg % nbn;

    const unsigned short* gA = A  + (long)bm * 128 * K;
    const unsigned short* gB = Bt + (long)bn * 128 * K;

    const long sgoff = (long)(tid >> 2) * K + (long)(((tid & 3) ^ ((tid >> 3) & 3)) * 8);
    const int swoff = wid * 512;

#define STAGE2(T, BUFO) do { \
        const long kb0 = (long)(T) * 32; \
        gll16(gB + sgoff + kb0, lds + (BUFO) + 4096 + swoff); \
        gll16(gA + sgoff + kb0, lds + (BUFO) + swoff); \
    } while (0)

    const int slot8 = (g ^ ((l15 >> 1) & 3)) * 8;
    f32x4 acc[4][2] = {};
    const int nkt = K >> 5;

    STAGE2(0, 0);
    STAGE2(1, 8192);

    int cur = 0, nx1 = 8192, nx2 = 16384;
    for (int t = 0; t < nkt; ++t) {
        if (t < nkt - 1) { VMCNT(2); } else { VMCNT(0); }
        BAR(); SCHED0();
        if (t + 2 < nkt) STAGE2(t + 2, nx2);

        bf16x8 af[4], bv[2];
#pragma unroll
        for (int mf = 0; mf < 4; mf++)
            af[mf] = *(const bf16x8*)&lds[cur + (wm * 64 + mf * 16 + l15) * 32 + slot8];
#pragma unroll
        for (int nf = 0; nf < 2; nf++)
            bv[nf] = *(const bf16x8*)&lds[cur + 4096 + (wn * 32 + nf * 16 + l15) * 32 + slot8];
        PRIO(1);
#pragma unroll
        for (int mf = 0; mf < 4; mf++)
#pragma unroll
            for (int nf = 0; nf < 2; nf++)
                acc[mf][nf] = __builtin_amdgcn_mfma_f32_16x16x32_bf16(af[mf], bv[nf], acc[mf][nf], 0, 0, 0);
        PRIO(0);
        const int tmp = cur; cur = nx1; nx1 = nx2; nx2 = tmp;
    }
#undef STAGE2

    float bvv[2];
#pragma unroll
    for (int nf = 0; nf < 2; nf++)
        bvv[nf] = bias0[bn * 128 + wn * 32 + nf * 16 + l15];
#pragma unroll
    for (int mf = 0; mf < 4; mf++) {
#pragma unroll
        for (int r = 0; r < 4; r++) {
            const long row = bm * 128 + wm * 64 + mf * 16 + g * 4 + r;
#pragma unroll
            for (int nf = 0; nf < 2; nf++)
                Cf[row * N + bn * 128 + wn * 32 + nf * 16 + l15] = acc[mf][nf][r] + bvv[nf];
        }
    }
}

// ---------------- k/v inverse-norm tables (no rewrite) ----------------
__global__ __launch_bounds__(256) void knvn_k(const unsigned short* __restrict__ qkv,
                                              float* __restrict__ kinv,
                                              float* __restrict__ vinv) {
    const int tid = threadIdx.x, lane = tid & 63, w = tid >> 6;
    const int s = blockIdx.x * 4 + w;
    const int row = s >> 3, h = s & 7;
    const unsigned short* pk = qkv + (long)row * 2304 + 768 + h * 96;
    float k0 = 0.f, k1 = 0.f, v0 = 0.f, v1 = 0.f;
    if (lane < 48) {
        unsigned a = *(const unsigned*)(pk + lane * 2);
        unsigned b = *(const unsigned*)(pk + 768 + lane * 2);
        k0 = b2f((unsigned short)(a & 0xffffu)); k1 = b2f((unsigned short)(a >> 16));
        v0 = b2f((unsigned short)(b & 0xffffu)); v1 = b2f((unsigned short)(b >> 16));
    }
    float sk = k0 * k0 + k1 * k1;
    float sv = v0 * v0 + v1 * v1;
#pragma unroll
    for (int m = 1; m < 64; m <<= 1) { sk += __shfl_xor(sk, m); sv += __shfl_xor(sv, m); }
    if (lane == 0) {
        kinv[h * 16384 + row] = 1.f / fmaxf(sqrtf(sk), 1e-12f);
        vinv[h * 16384 + row] = 1.f / fmaxf(sqrtf(sv), 1e-12f);
    }
}

// ---------------- fused attention per (bt, head, 128-row q-block) ----------------
// r18 measured-best form: double-buffered K/V (1 barrier/tile), Q global->reg,
// slim Ps, T14 split-wave prefetch, T5 setprio, __expf softmax (no max needed).
__global__ __launch_bounds__(512, 2) void attn_k(const unsigned short* __restrict__ qkv,
                                                 const float* __restrict__ kinv,
                                                 const float* __restrict__ vinv,
                                                 unsigned short* __restrict__ obuf) {
    constexpr float SCALE = 0.1020620726159658f;  // 1/sqrt(96)
    __shared__ unsigned short Ps[128 * 72];       // P' (rows owned per wave)
    __shared__ unsigned short Ks[2][64 * 104];    // K tiles, double-buffered
    __shared__ unsigned short Vt[2][96 * 72];     // V^T tiles, double-buffered
    __shared__ float kinv_s[2][64], vinv_s[2][64];

    const int tid = threadIdx.x, lane = tid & 63, w = tid >> 6;
    const int bid0 = blockIdx.x;
    const int bid = (bid0 & 7) * 128 + (bid0 >> 3);   // XCD swizzle (1024 % 8 == 0)
    const int qt = bid & 3, h = (bid >> 2) & 7, bt = bid >> 5;
    const long rowbase = (long)bt * 512 * 2304 + h * 96;
    const int l15 = lane & 15;
    const int g = lane >> 4;
    const int ko = g * 8;

    // ---- Q fragments: straight from global (row = qt*128 + w*16 + l15, L2-warm) ----
    bf16x8 qf[3];
    {
        const unsigned short* qrow = qkv + rowbase + (long)(qt * 128 + w * 16 + l15) * 2304;
#pragma unroll
        for (int ks = 0; ks < 3; ks++)
            qf[ks] = *(const bf16x8*)&qrow[ks * 32 + ko];
    }

    // ---- stage K/V tile 0 into buffer 0 (split-wave, paired-key V transpose) ----
    if (tid < 256) {
#pragma unroll
        for (int j = 0; j < 3; j++) {
            const int c = tid + j * 256;
            const int r = c / 12, d8 = (c % 12) * 8;
            *(int4v*)&Ks[0][r * 104 + d8] = *(const int4v*)&qkv[rowbase + 768 + (long)r * 2304 + d8];
        }
    } else {
        const int tid2 = tid - 256;
#pragma unroll
        for (int j = 0; j < 2; j++) {
            const int c = tid2 + j * 256;
            if (c < 384) {
                const int kp = c & 31, d8c = c >> 5;
                const unsigned short* vsrc = &qkv[rowbase + 1536 + (long)(2 * kp) * 2304 + d8c * 8];
                int4v v0 = *(const int4v*)vsrc;
                int4v v1 = *(const int4v*)(vsrc + 2304);
                const unsigned short* p0 = (const unsigned short*)&v0;
                const unsigned short* p1 = (const unsigned short*)&v1;
#pragma unroll
                for (int i = 0; i < 8; i++)
                    *(unsigned*)&Vt[0][(d8c * 8 + i) * 72 + 2 * kp] =
                        (unsigned)p0[i] | ((unsigned)p1[i] << 16);
            }
        }
    }
    if (tid < 64)       kinv_s[0][tid]      = kinv[h * 16384 + bt * 512 + tid];
    else if (tid < 128) vinv_s[0][tid - 64] = vinv[h * 16384 + bt * 512 + tid - 64];
    __syncthreads();

    // q-row scale = SCALE / ||q_row|| (f32)
    float ssq = 0.f;
#pragma unroll
    for (int ks = 0; ks < 3; ks++)
#pragma unroll
        for (int j = 0; j < 8; j++) {
            const float f = b2f((unsigned short)qf[ks][j]);
            ssq += f * f;
        }
    ssq += __shfl_xor(ssq, 16);
    ssq += __shfl_xor(ssq, 32);
    const float qs = SCALE / fmaxf(sqrtf(ssq), 1e-12f);

    float l_run = 0.f;
    f32x4 oacc[6] = {};

    for (int kt = 0; kt < 8; kt++) {
        const int cb = kt & 1, nb = cb ^ 1;

        // ---- T14: prefetch next K/V tile into registers ----
        int4v preg[4];
        float tn = 0.f;
        if (kt < 7) {
            if (tid < 256) {
                const long kb = rowbase + 768 + (long)((kt + 1) * 64) * 2304;
#pragma unroll
                for (int j = 0; j < 3; j++) {
                    const int c = tid + j * 256;
                    preg[j] = *(const int4v*)&qkv[kb + (long)(c / 12) * 2304 + (c % 12) * 8];
                }
            } else {
                const int tid2 = tid - 256;
                const long vb = rowbase + 1536 + (long)((kt + 1) * 64) * 2304;
#pragma unroll
                for (int j = 0; j < 2; j++) {
                    const int c = tid2 + j * 256;
                    if (c < 384) {
                        const int kp = c & 31, d8c = c >> 5;
                        const unsigned short* vsrc = &qkv[vb + (long)(2 * kp) * 2304 + d8c * 8];
                        preg[2 * j]     = *(const int4v*)vsrc;
                        preg[2 * j + 1] = *(const int4v*)(vsrc + 2304);
                    }
                }
            }
            if (tid < 64)       tn = kinv[h * 16384 + bt * 512 + (kt + 1) * 64 + tid];
            else if (tid < 128) tn = vinv[h * 16384 + bt * 512 + (kt + 1) * 64 + tid - 64];
        }

        // ---- S^T = mfma(K_raw, Q_raw): rows = key, cols = q ----
        f32x4 sacc[4] = {};
        PRIO(1);
#pragma unroll
        for (int ks = 0; ks < 3; ks++) {
#pragma unroll
            for (int kf = 0; kf < 4; kf++) {
                bf16x8 af = *(const bf16x8*)&Ks[cb][(kf * 16 + l15) * 104 + ks * 32 + ko];
                sacc[kf] = __builtin_amdgcn_mfma_f32_16x16x32_bf16(af, qf[ks], sacc[kf], 0, 0, 0);
            }
        }
        PRIO(0);

        // ---- softmax without max: p = exp(s*qs*kinv); fold vinv into P' ----
        float p[16];
        float s = 0.f;
#pragma unroll
        for (int kf = 0; kf < 4; kf++)
#pragma unroll
            for (int r = 0; r < 4; r++) {
                const float pv = __expf(sacc[kf][r] * qs * kinv_s[cb][kf * 16 + g * 4 + r]);
                s += pv;
                p[kf * 4 + r] = pv * vinv_s[cb][kf * 16 + g * 4 + r];
            }
        s += __shfl_xor(s, 16);
        s += __shfl_xor(s, 32);
        l_run += s;

        // ---- pack P' (row q = w*16+l15, cols keys) into Ps, paired u32 (wave-local) ----
        {
            unsigned* prow = (unsigned*)&Ps[(w * 16 + l15) * 72];
#pragma unroll
            for (int kf = 0; kf < 4; kf++)
#pragma unroll
                for (int rp = 0; rp < 2; rp++) {
                    unsigned pk = (unsigned)f2b(p[kf * 4 + 2 * rp]) |
                                  ((unsigned)f2b(p[kf * 4 + 2 * rp + 1]) << 16);
                    prow[kf * 8 + g * 2 + rp] = pk;
                }
        }

        // ---- O += P' * V_raw ----
        PRIO(1);
#pragma unroll
        for (int ks = 0; ks < 2; ks++) {
            bf16x8 pa = *(const bf16x8*)&Ps[(w * 16 + l15) * 72 + ks * 32 + ko];
#pragma unroll
            for (int nf = 0; nf < 6; nf++) {
                bf16x8 vb = *(const bf16x8*)&Vt[cb][(nf * 16 + l15) * 72 + ks * 32 + ko];
                oacc[nf] = __builtin_amdgcn_mfma_f32_16x16x32_bf16(pa, vb, oacc[nf], 0, 0, 0);
            }
        }
        PRIO(0);

        // ---- write prefetched regs -> buffer nb (disjoint from cb readers), then ONE barrier ----
        if (kt < 7) {
            if (tid < 256) {
#pragma unroll
                for (int j = 0; j < 3; j++) {
                    const int c = tid + j * 256;
                    *(int4v*)&Ks[nb][(c / 12) * 104 + (c % 12) * 8] = preg[j];
                }
            } else {
                const int tid2 = tid - 256;
#pragma unroll
                for (int j = 0; j < 2; j++) {
                    const int c = tid2 + j * 256;
                    if (c < 384) {
                        const int kp = c & 31, d8c = c >> 5;
                        const unsigned short* p0 = (const unsigned short*)&preg[2 * j];
                        const unsigned short* p1 = (const unsigned short*)&preg[2 * j + 1];
#pragma unroll
                        for (int i = 0; i < 8; i++)
                            *(unsigned*)&Vt[nb][(d8c * 8 + i) * 72 + 2 * kp] =
                                (unsigned)p0[i] | ((unsigned)p1[i] << 16);
                    }
                }
            }
            if (tid < 64)       kinv_s[nb][tid]      = tn;
            else if (tid < 128) vinv_s[nb][tid - 64] = tn;
            __syncthreads();
        }
    }

    // ---- write O tile ----
    const float inv = 1.f / l_run;
    float invr[4];
#pragma unroll
    for (int r = 0; r < 4; r++) invr[r] = __shfl(inv, g * 4 + r);
#pragma unroll
    for (int r = 0; r < 4; r++) {
        const int row = w * 16 + g * 4 + r;
        const long gr = ((long)(bt * 512 + qt * 128 + row)) * 768 + h * 96;
#pragma unroll
        for (int nf = 0; nf < 6; nf++)
            obuf[gr + nf * 16 + l15] = f2b(oacc[nf][r] * invr[r]);
    }
}

extern "C" void kernel_launch(void* const* d_in, const int* in_sizes, int n_in,
                              void* d_out, int out_size, void* d_ws, size_t ws_size,
                              hipStream_t stream) {
    const float* x   = (const float*)d_in[0];
    const float* Wq  = (const float*)d_in[1];
    const float* bq  = (const float*)d_in[2];
    const float* Wkv = (const float*)d_in[3];
    const float* bkv = (const float*)d_in[4];
    const float* Wm  = (const float*)d_in[5];
    const float* bm  = (const float*)d_in[6];
    float* out = (float*)d_out;

    char* ws = (char*)d_ws;
    unsigned short* xb  = (unsigned short*)ws;                   // 16384x768 bf16 (dead after gemm0)
    float*          vinv = (float*)ws;                           // overlays xb: 512 KB
    float*          kinv = (float*)(ws + 524288);                // overlays xb: 512 KB
    unsigned short* wt  = (unsigned short*)(ws + 25165824);      // 3072x768 bf16
    unsigned short* qkv = (unsigned short*)(ws + 29884416);      // 16384x2304 bf16 (raw +bias)
    unsigned short* ob  = (unsigned short*)(ws + 105381888);     // 16384x768 bf16

    static bool attr_set = false;
    if (!attr_set) {
        hipFuncSetAttribute((const void*)gemm_k<0>, hipFuncAttributeMaxDynamicSharedMemorySize, 73728);
        hipFuncSetAttribute((const void*)gemm128_k, hipFuncAttributeMaxDynamicSharedMemorySize, 49152);
        attr_set = true;
    }

    // fused cast + weight pack (one launch)
    prep_k<<<dim3(12864), dim3(256), 0, stream>>>(x, xb, Wq, Wkv, Wm, wt);
    // QKV projection + bias: r5 3-buffer gemm (measured 77us), grid 64bm x 18bn = 1152
    gemm_k<0><<<dim3(1152), dim3(512), 73728, stream>>>(xb, wt, bq, bkv, qkv, nullptr, 2304, 768, 18);
    // k/v inverse-norm tables (overlay xb, dead by now)
    knvn_k<<<dim3(32768), dim3(256), 0, stream>>>(qkv, kinv, vinv);
    // fused attention: double-buffered K/V, 1 barrier/tile, setprio MFMA clusters
    attn_k<<<dim3(1024), dim3(512), 0, stream>>>(qkv, kinv, vinv, ob);
    // output projection + bias -> fp32: grid 128bm x 6bn = 768
    gemm128_k<<<dim3(768), dim3(512), 49152, stream>>>(ob, wt + (long)2304 * 768, bm, out, 768, 768, 6);
}

// Round 21
// 174.294 us; speedup vs baseline: 1.2885x; 1.1066x over previous
//
#include <hip/hip_runtime.h>
#include <hip/hip_bf16.h>

// Problem constants: B=4,T=8,L=512,C=768,H=8,HD=96.  M = B*T*L = 16384.

typedef __attribute__((ext_vector_type(8))) short bf16x8;
typedef __attribute__((ext_vector_type(4))) float f32x4;
typedef __attribute__((ext_vector_type(4))) int int4v;

__device__ __forceinline__ float b2f(unsigned short u) {
    return __uint_as_float(((unsigned)u) << 16);
}
__device__ __forceinline__ unsigned short f2b(float f) {
    unsigned u = __float_as_uint(f);
    u = (u + 0x7fffu + ((u >> 16) & 1u)) >> 16;   // RNE
    return (unsigned short)u;
}

__device__ __forceinline__ void gll16(const unsigned short* g, unsigned short* l) {
    __builtin_amdgcn_global_load_lds((const __attribute__((address_space(1))) unsigned int*)g,
                                     (__attribute__((address_space(3))) unsigned int*)l, 16, 0, 0);
}

#define VMCNT(n) asm volatile("s_waitcnt vmcnt(" #n ")" ::: "memory")
#define BAR()    __builtin_amdgcn_s_barrier()
#define SCHED0() __builtin_amdgcn_sched_barrier(0)
#define PRIO(x)  __builtin_amdgcn_s_setprio(x)

// ---------------- fused prep: cast x->bf16 (blocks 0..12287) + pack W^T (blocks 12288..12863) ----------------
__global__ __launch_bounds__(256) void prep_k(const float* __restrict__ x,
                                              unsigned short* __restrict__ xb,
                                              const float* __restrict__ Wq,
                                              const float* __restrict__ Wkv,
                                              const float* __restrict__ Wm,
                                              unsigned short* __restrict__ Wt) {
    __shared__ float tile[64][65];
    const int tid = threadIdx.x;
    if (blockIdx.x < 12288) {
        const int i = blockIdx.x * 256 + tid;
        float4 v = ((const float4*)x)[i];
        ushort4 o;
        o.x = f2b(v.x); o.y = f2b(v.y); o.z = f2b(v.z); o.w = f2b(v.w);
        ((ushort4*)xb)[i] = o;
        return;
    }
    const int pb = blockIdx.x - 12288;
    const int tn = pb % 48;
    const int tk = pb / 48;
    const int n0 = tn * 64, k0 = tk * 64;
    const float* src; int ldn, coff;
    if (n0 < 768)       { src = Wq;  ldn = 768;  coff = n0; }
    else if (n0 < 2304) { src = Wkv; ldn = 1536; coff = n0 - 768; }
    else                { src = Wm;  ldn = 768;  coff = n0 - 2304; }
    const int j = tid & 63;
    for (int i = tid >> 6; i < 64; i += 4)
        tile[i][j] = src[(k0 + i) * ldn + coff + j];
    __syncthreads();
    const int ii = tid & 63;
    for (int jj = tid >> 6; jj < 64; jj += 4)
        Wt[(long)(n0 + jj) * 768 + k0 + ii] = f2b(tile[ii][jj]);
}

// ---------------- 256x128 pipelined GEMM, 3-buffer LDS, 2 blocks/CU (r5 known-good, 77us) ----------------
template <int EPI>
__global__ __launch_bounds__(512, 4) void gemm_k(const unsigned short* __restrict__ A,
                                                 const unsigned short* __restrict__ Bt,
                                                 const float* __restrict__ bias0,
                                                 const float* __restrict__ bias1,
                                                 unsigned short* __restrict__ Cb,
                                                 float* __restrict__ Cf,
                                                 int N, int K, int nbn) {
    extern __shared__ unsigned short lds[];   // 3 x 12288 ushorts
    const int tid = threadIdx.x;
    const int lane = tid & 63, wid = tid >> 6;
    const int wm = wid >> 1, wn = wid & 1;
    const int l15 = lane & 15, g = lane >> 4;

    const int nwg = gridDim.x;
    const int wg = (blockIdx.x & 7) * (nwg >> 3) + (blockIdx.x >> 3);
    const int bm = wg / nbn, bn = wg % nbn;

    const unsigned short* gA = A  + (long)bm * 256 * K;
    const unsigned short* gB = Bt + (long)bn * 128 * K;

    const long sgoff = (long)(tid >> 2) * K + (long)(((tid & 3) ^ ((tid >> 3) & 3)) * 8);
    const int swoff = wid * 512;

#define STAGE_ALL(T, BUFO) do { \
        const long kb0 = (long)(T) * 32; \
        gll16(gB + sgoff + kb0, lds + (BUFO) + 8192 + swoff); \
        gll16(gA + sgoff + kb0, lds + (BUFO) + swoff); \
        gll16(gA + sgoff + kb0 + (long)128 * K, lds + (BUFO) + 4096 + swoff); \
    } while (0)

    const int slot8 = (g ^ ((l15 >> 1) & 3)) * 8;
    f32x4 acc[4][4] = {};
    const int nkt = K >> 5;

    STAGE_ALL(0, 0);
    STAGE_ALL(1, 12288);

    int cur = 0, nx1 = 12288, nx2 = 24576;
    for (int t = 0; t < nkt; ++t) {
        if (t < nkt - 1) { VMCNT(3); } else { VMCNT(0); }
        BAR(); SCHED0();
        if (t + 2 < nkt) STAGE_ALL(t + 2, nx2);

        bf16x8 af[4], bv[4];
#pragma unroll
        for (int mf = 0; mf < 4; mf++)
            af[mf] = *(const bf16x8*)&lds[cur + (wm * 64 + mf * 16 + l15) * 32 + slot8];
#pragma unroll
        for (int nf = 0; nf < 4; nf++)
            bv[nf] = *(const bf16x8*)&lds[cur + 8192 + (wn * 64 + nf * 16 + l15) * 32 + slot8];
        PRIO(1);
#pragma unroll
        for (int mf = 0; mf < 4; mf++)
#pragma unroll
            for (int nf = 0; nf < 4; nf++)
                acc[mf][nf] = __builtin_amdgcn_mfma_f32_16x16x32_bf16(af[mf], bv[nf], acc[mf][nf], 0, 0, 0);
        PRIO(0);
        const int tmp = cur; cur = nx1; nx1 = nx2; nx2 = tmp;
    }
#undef STAGE_ALL

    float bvv[4];
#pragma unroll
    for (int nf = 0; nf < 4; nf++) {
        const int col = bn * 128 + wn * 64 + nf * 16 + l15;
        bvv[nf] = (EPI == 0) ? ((col < 768) ? bias0[col] : bias1[col - 768]) : bias0[col];
    }
#pragma unroll
    for (int mf = 0; mf < 4; mf++) {
#pragma unroll
        for (int r = 0; r < 4; r++) {
            const long row = bm * 256 + wm * 64 + mf * 16 + g * 4 + r;
#pragma unroll
            for (int nf = 0; nf < 4; nf++) {
                const float v = acc[mf][nf][r] + bvv[nf];
                if (EPI == 0) {
                    const unsigned hh = f2b(v);
                    const unsigned oo = __shfl_xor((int)hh, 1);
                    if (!(lane & 1))
                        *(unsigned*)&Cb[row * N + bn * 128 + wn * 64 + nf * 16 + l15] =
                            (hh & 0xffffu) | (oo << 16);
                } else {
                    Cf[row * N + bn * 128 + wn * 64 + nf * 16 + l15] = v;
                }
            }
        }
    }
}

// ---------------- 128x128 GEMM for the output projection (fp32 out), 3 blocks/CU ----------------
__global__ __launch_bounds__(512, 6) void gemm128_k(const unsigned short* __restrict__ A,
                                                    const unsigned short* __restrict__ Bt,
                                                    const float* __restrict__ bias0,
                                                    float* __restrict__ Cf,
                                                    int N, int K, int nbn) {
    extern __shared__ unsigned short lds[];   // 3 x 8192 ushorts (A 4096 + B 4096)
    const int tid = threadIdx.x;
    const int lane = tid & 63, wid = tid >> 6;
    const int wm = wid >> 2, wn = wid & 3;
    const int l15 = lane & 15, g = lane >> 4;

    const int nwg = gridDim.x;
    const int wg = (blockIdx.x & 7) * (nwg >> 3) + (blockIdx.x >> 3);
    const int bm = wg / nbn, bn = wg % nbn;

    const unsigned short* gA = A  + (long)bm * 128 * K;
    const unsigned short* gB = Bt + (long)bn * 128 * K;

    const long sgoff = (long)(tid >> 2) * K + (long)(((tid & 3) ^ ((tid >> 3) & 3)) * 8);
    const int swoff = wid * 512;

#define STAGE2(T, BUFO) do { \
        const long kb0 = (long)(T) * 32; \
        gll16(gB + sgoff + kb0, lds + (BUFO) + 4096 + swoff); \
        gll16(gA + sgoff + kb0, lds + (BUFO) + swoff); \
    } while (0)

    const int slot8 = (g ^ ((l15 >> 1) & 3)) * 8;
    f32x4 acc[4][2] = {};
    const int nkt = K >> 5;

    STAGE2(0, 0);
    STAGE2(1, 8192);

    int cur = 0, nx1 = 8192, nx2 = 16384;
    for (int t = 0; t < nkt; ++t) {
        if (t < nkt - 1) { VMCNT(2); } else { VMCNT(0); }
        BAR(); SCHED0();
        if (t + 2 < nkt) STAGE2(t + 2, nx2);

        bf16x8 af[4], bv[2];
#pragma unroll
        for (int mf = 0; mf < 4; mf++)
            af[mf] = *(const bf16x8*)&lds[cur + (wm * 64 + mf * 16 + l15) * 32 + slot8];
#pragma unroll
        for (int nf = 0; nf < 2; nf++)
            bv[nf] = *(const bf16x8*)&lds[cur + 4096 + (wn * 32 + nf * 16 + l15) * 32 + slot8];
        PRIO(1);
#pragma unroll
        for (int mf = 0; mf < 4; mf++)
#pragma unroll
            for (int nf = 0; nf < 2; nf++)
                acc[mf][nf] = __builtin_amdgcn_mfma_f32_16x16x32_bf16(af[mf], bv[nf], acc[mf][nf], 0, 0, 0);
        PRIO(0);
        const int tmp = cur; cur = nx1; nx1 = nx2; nx2 = tmp;
    }
#undef STAGE2

    float bvv[2];
#pragma unroll
    for (int nf = 0; nf < 2; nf++)
        bvv[nf] = bias0[bn * 128 + wn * 32 + nf * 16 + l15];
#pragma unroll
    for (int mf = 0; mf < 4; mf++) {
#pragma unroll
        for (int r = 0; r < 4; r++) {
            const long row = bm * 128 + wm * 64 + mf * 16 + g * 4 + r;
#pragma unroll
            for (int nf = 0; nf < 2; nf++)
                Cf[row * N + bn * 128 + wn * 32 + nf * 16 + l15] = acc[mf][nf][r] + bvv[nf];
        }
    }
}

// ---------------- fused attention per (bt, head, 128-row q-block) ----------------
// r20 structure + FUSED k/v norms: staging threads write per-chunk sum-of-squares
// partials to plain LDS arrays (NO atomics — r4's failure mode); a 128-thread
// sum-pass + rsqrt at tile top fills kinv_s/vinv_s, published by a mid-tile
// barrier (which also licenses partial-buffer overwrite in the writeback).
// knvn_k kernel (51 MB HBM re-read) deleted.
__global__ __launch_bounds__(512, 2) void attn_k(const unsigned short* __restrict__ qkv,
                                                 unsigned short* __restrict__ obuf) {
    constexpr float SCALE = 0.1020620726159658f;  // 1/sqrt(96)
    __shared__ unsigned short Ps[128 * 72];       // P' (rows owned per wave)
    __shared__ unsigned short Ks[2][64 * 104];    // K tiles, double-buffered
    __shared__ unsigned short Vt[2][96 * 72];     // V^T tiles, double-buffered
    __shared__ float ksum_p[768];                 // [row][m] linear: addr = row*12+m = c
    __shared__ float vsum_p[768];                 // [m][row]:        addr = m*64+row
    __shared__ float kinv_s[64], vinv_s[64];      // single-buffered (BAR-separated)

    const int tid = threadIdx.x, lane = tid & 63, w = tid >> 6;
    const int bid0 = blockIdx.x;
    const int bid = (bid0 & 7) * 128 + (bid0 >> 3);   // XCD swizzle (1024 % 8 == 0)
    const int qt = bid & 3, h = (bid >> 2) & 7, bt = bid >> 5;
    const long rowbase = (long)bt * 512 * 2304 + h * 96;
    const int l15 = lane & 15;
    const int g = lane >> 4;
    const int ko = g * 8;

    // ---- Q fragments: straight from global (row = qt*128 + w*16 + l15, L2-warm) ----
    bf16x8 qf[3];
    {
        const unsigned short* qrow = qkv + rowbase + (long)(qt * 128 + w * 16 + l15) * 2304;
#pragma unroll
        for (int ks = 0; ks < 3; ks++)
            qf[ks] = *(const bf16x8*)&qrow[ks * 32 + ko];
    }

    // ---- stage K/V tile 0 into buffer 0 + norm partials ----
    if (tid < 256) {
#pragma unroll
        for (int j = 0; j < 3; j++) {
            const int c = tid + j * 256;
            const int r = c / 12, d8 = (c % 12) * 8;
            int4v kv = *(const int4v*)&qkv[rowbase + 768 + (long)r * 2304 + d8];
            *(int4v*)&Ks[0][r * 104 + d8] = kv;
            const unsigned short* kp8 = (const unsigned short*)&kv;
            float s8 = 0.f;
#pragma unroll
            for (int i = 0; i < 8; i++) { const float f = b2f(kp8[i]); s8 += f * f; }
            ksum_p[c] = s8;
        }
    } else {
        const int tid2 = tid - 256;
#pragma unroll
        for (int j = 0; j < 2; j++) {
            const int c = tid2 + j * 256;
            if (c < 384) {
                const int kp = c & 31, d8c = c >> 5;
                const unsigned short* vsrc = &qkv[rowbase + 1536 + (long)(2 * kp) * 2304 + d8c * 8];
                int4v v0 = *(const int4v*)vsrc;
                int4v v1 = *(const int4v*)(vsrc + 2304);
                const unsigned short* p0 = (const unsigned short*)&v0;
                const unsigned short* p1 = (const unsigned short*)&v1;
                float s0 = 0.f, s1 = 0.f;
#pragma unroll
                for (int i = 0; i < 8; i++) {
                    const float f0 = b2f(p0[i]); s0 += f0 * f0;
                    const float f1 = b2f(p1[i]); s1 += f1 * f1;
                    *(unsigned*)&Vt[0][(d8c * 8 + i) * 72 + 2 * kp] =
                        (unsigned)p0[i] | ((unsigned)p1[i] << 16);
                }
                vsum_p[d8c * 64 + 2 * kp]     = s0;
                vsum_p[d8c * 64 + 2 * kp + 1] = s1;
            }
        }
    }
    __syncthreads();

    // q-row scale = SCALE / ||q_row|| (f32)
    float ssq = 0.f;
#pragma unroll
    for (int ks = 0; ks < 3; ks++)
#pragma unroll
        for (int j = 0; j < 8; j++) {
            const float f = b2f((unsigned short)qf[ks][j]);
            ssq += f * f;
        }
    ssq += __shfl_xor(ssq, 16);
    ssq += __shfl_xor(ssq, 32);
    const float qs = SCALE / fmaxf(sqrtf(ssq), 1e-12f);

    float l_run = 0.f;
    f32x4 oacc[6] = {};

    for (int kt = 0; kt < 8; kt++) {
        const int cb = kt & 1, nb = cb ^ 1;

        // ---- T14: prefetch next K/V tile into registers ----
        int4v preg[4];
        if (kt < 7) {
            if (tid < 256) {
                const long kb = rowbase + 768 + (long)((kt + 1) * 64) * 2304;
#pragma unroll
                for (int j = 0; j < 3; j++) {
                    const int c = tid + j * 256;
                    preg[j] = *(const int4v*)&qkv[kb + (long)(c / 12) * 2304 + (c % 12) * 8];
                }
            } else {
                const int tid2 = tid - 256;
                const long vb = rowbase + 1536 + (long)((kt + 1) * 64) * 2304;
#pragma unroll
                for (int j = 0; j < 2; j++) {
                    const int c = tid2 + j * 256;
                    if (c < 384) {
                        const int kp = c & 31, d8c = c >> 5;
                        const unsigned short* vsrc = &qkv[vb + (long)(2 * kp) * 2304 + d8c * 8];
                        preg[2 * j]     = *(const int4v*)vsrc;
                        preg[2 * j + 1] = *(const int4v*)(vsrc + 2304);
                    }
                }
            }
        }

        // ---- sum pass: norms of tile kt from staged partials (threads 0..127) ----
        if (tid < 64) {
            float s = 0.f;
#pragma unroll
            for (int m = 0; m < 12; m++) s += ksum_p[tid * 12 + m];
            kinv_s[tid] = 1.f / fmaxf(sqrtf(s), 1e-12f);
        } else if (tid < 128) {
            float s = 0.f;
#pragma unroll
            for (int m = 0; m < 12; m++) s += vsum_p[m * 64 + (tid - 64)];
            vinv_s[tid - 64] = 1.f / fmaxf(sqrtf(s), 1e-12f);
        }

        // ---- S^T = mfma(K_raw, Q_raw): rows = key, cols = q ----
        f32x4 sacc[4] = {};
        PRIO(1);
#pragma unroll
        for (int ks = 0; ks < 3; ks++) {
#pragma unroll
            for (int kf = 0; kf < 4; kf++) {
                bf16x8 af = *(const bf16x8*)&Ks[cb][(kf * 16 + l15) * 104 + ks * 32 + ko];
                sacc[kf] = __builtin_amdgcn_mfma_f32_16x16x32_bf16(af, qf[ks], sacc[kf], 0, 0, 0);
            }
        }
        PRIO(0);

        // BAR2: publish kinv_s/vinv_s; also separates partial reads from writeback overwrite
        __syncthreads();

        // ---- softmax without max: p = exp(s*qs*kinv); fold vinv into P' ----
        float p[16];
        float s = 0.f;
#pragma unroll
        for (int kf = 0; kf < 4; kf++)
#pragma unroll
            for (int r = 0; r < 4; r++) {
                const float pv = __expf(sacc[kf][r] * qs * kinv_s[kf * 16 + g * 4 + r]);
                s += pv;
                p[kf * 4 + r] = pv * vinv_s[kf * 16 + g * 4 + r];
            }
        s += __shfl_xor(s, 16);
        s += __shfl_xor(s, 32);
        l_run += s;

        // ---- pack P' (row q = w*16+l15, cols keys) into Ps, paired u32 (wave-local) ----
        {
            unsigned* prow = (unsigned*)&Ps[(w * 16 + l15) * 72];
#pragma unroll
            for (int kf = 0; kf < 4; kf++)
#pragma unroll
                for (int rp = 0; rp < 2; rp++) {
                    unsigned pk = (unsigned)f2b(p[kf * 4 + 2 * rp]) |
                                  ((unsigned)f2b(p[kf * 4 + 2 * rp + 1]) << 16);
                    prow[kf * 8 + g * 2 + rp] = pk;
                }
        }

        // ---- O += P' * V_raw ----
        PRIO(1);
#pragma unroll
        for (int ks = 0; ks < 2; ks++) {
            bf16x8 pa = *(const bf16x8*)&Ps[(w * 16 + l15) * 72 + ks * 32 + ko];
#pragma unroll
            for (int nf = 0; nf < 6; nf++) {
                bf16x8 vb = *(const bf16x8*)&Vt[cb][(nf * 16 + l15) * 72 + ks * 32 + ko];
                oacc[nf] = __builtin_amdgcn_mfma_f32_16x16x32_bf16(pa, vb, oacc[nf], 0, 0, 0);
            }
        }
        PRIO(0);

        // ---- writeback: K/V -> buffer nb + fresh partials (single buffers, post-BAR2) ----
        if (kt < 7) {
            if (tid < 256) {
#pragma unroll
                for (int j = 0; j < 3; j++) {
                    const int c = tid + j * 256;
                    *(int4v*)&Ks[nb][(c / 12) * 104 + (c % 12) * 8] = preg[j];
                    const unsigned short* kp8 = (const unsigned short*)&preg[j];
                    float s8 = 0.f;
#pragma unroll
                    for (int i = 0; i < 8; i++) { const float f = b2f(kp8[i]); s8 += f * f; }
                    ksum_p[c] = s8;
                }
            } else {
                const int tid2 = tid - 256;
#pragma unroll
                for (int j = 0; j < 2; j++) {
                    const int c = tid2 + j * 256;
                    if (c < 384) {
                        const int kp = c & 31, d8c = c >> 5;
                        const unsigned short* p0 = (const unsigned short*)&preg[2 * j];
                        const unsigned short* p1 = (const unsigned short*)&preg[2 * j + 1];
                        float s0 = 0.f, s1 = 0.f;
#pragma unroll
                        for (int i = 0; i < 8; i++) {
                            const float f0 = b2f(p0[i]); s0 += f0 * f0;
                            const float f1 = b2f(p1[i]); s1 += f1 * f1;
                            *(unsigned*)&Vt[nb][(d8c * 8 + i) * 72 + 2 * kp] =
                                (unsigned)p0[i] | ((unsigned)p1[i] << 16);
                        }
                        vsum_p[d8c * 64 + 2 * kp]     = s0;
                        vsum_p[d8c * 64 + 2 * kp + 1] = s1;
                    }
                }
            }
            __syncthreads();
        }
    }

    // ---- write O tile ----
    const float inv = 1.f / l_run;
    float invr[4];
#pragma unroll
    for (int r = 0; r < 4; r++) invr[r] = __shfl(inv, g * 4 + r);
#pragma unroll
    for (int r = 0; r < 4; r++) {
        const int row = w * 16 + g * 4 + r;
        const long gr = ((long)(bt * 512 + qt * 128 + row)) * 768 + h * 96;
#pragma unroll
        for (int nf = 0; nf < 6; nf++)
            obuf[gr + nf * 16 + l15] = f2b(oacc[nf][r] * invr[r]);
    }
}

extern "C" void kernel_launch(void* const* d_in, const int* in_sizes, int n_in,
                              void* d_out, int out_size, void* d_ws, size_t ws_size,
                              hipStream_t stream) {
    const float* x   = (const float*)d_in[0];
    const float* Wq  = (const float*)d_in[1];
    const float* bq  = (const float*)d_in[2];
    const float* Wkv = (const float*)d_in[3];
    const float* bkv = (const float*)d_in[4];
    const float* Wm  = (const float*)d_in[5];
    const float* bm  = (const float*)d_in[6];
    float* out = (float*)d_out;

    char* ws = (char*)d_ws;
    unsigned short* xb  = (unsigned short*)ws;                   // 16384x768 bf16 (dead after gemm0)
    unsigned short* wt  = (unsigned short*)(ws + 25165824);      // 3072x768 bf16
    unsigned short* qkv = (unsigned short*)(ws + 29884416);      // 16384x2304 bf16 (raw +bias)
    unsigned short* ob  = (unsigned short*)(ws + 105381888);     // 16384x768 bf16

    static bool attr_set = false;
    if (!attr_set) {
        hipFuncSetAttribute((const void*)gemm_k<0>, hipFuncAttributeMaxDynamicSharedMemorySize, 73728);
        hipFuncSetAttribute((const void*)gemm128_k, hipFuncAttributeMaxDynamicSharedMemorySize, 49152);
        attr_set = true;
    }

    // fused cast + weight pack (one launch)
    prep_k<<<dim3(12864), dim3(256), 0, stream>>>(x, xb, Wq, Wkv, Wm, wt);
    // QKV projection + bias: r5 3-buffer gemm (measured 77us), grid 64bm x 18bn = 1152
    gemm_k<0><<<dim3(1152), dim3(512), 73728, stream>>>(xb, wt, bq, bkv, qkv, nullptr, 2304, 768, 18);
    // fused attention: double-buffered K/V + IN-KERNEL k/v norms (knvn pass deleted)
    attn_k<<<dim3(1024), dim3(512), 0, stream>>>(qkv, ob);
    // output projection + bias -> fp32: grid 128bm x 6bn = 768
    gemm128_k<<<dim3(768), dim3(512), 49152, stream>>>(ob, wt + (long)2304 * 768, bm, out, 768, 768, 6);
}